// Round 8
// baseline (86.884 us; speedup 1.0000x reference)
//
#include <hip/hip_runtime.h>
#include <math.h>

// Problem dims (fixed by reference setup_inputs)
#define B 2
#define C 128
#define H 128
#define W 256
#define K 20
#define HW (H * W)
#define SO_STRIDE 260   // s_o row stride in floats (float4-aligned, bank-skewed)

typedef float f32x4 __attribute__((ext_vector_type(4)));
typedef short bf16x8 __attribute__((ext_vector_type(8)));

// round-to-nearest-even fp32 -> bf16 bits (finite inputs)
__device__ __forceinline__ unsigned f2bf_bits(float x) {
    unsigned u = __float_as_uint(x);
    return (u + 0x7FFFu + ((u >> 16) & 1u)) >> 16;
}
__device__ __forceinline__ float bf_to_f(unsigned bits) {
    return __uint_as_float(bits << 16);
}

// One block per (b,h): 1024 threads = 16 waves; wave = 16-w m-tile (m0 = wave*16).
// Features are read from HBM exactly once: the norm loop keeps the loaded row in
// registers, applies rn (wave-local shuffle reduce, no barrier), and stages
// bf16(f*rn) into a uint-packed LDS tile. Two 64-c passes (32 KB tile).
// dist^2 = S + P - 2*dot with S from the rounded values => ||bf(u)-bf(pn)||^2 >= 0.
__global__ __launch_bounds__(1024) void isomax_fused(
    const float* __restrict__ feats, const float* __restrict__ protos,
    const float* __restrict__ dscale, float* __restrict__ out)
{
    __shared__ __align__(16) unsigned s_u32[64 * 128];  // 32 KB bf16 tile [cc][(w^swz)/2]
    __shared__ float s_rp[32];              // proto inv-norms
    __shared__ float s_pp[32];              // sum_c bf(pn[k,c])^2
    __shared__ float s_S[W];                // S[w] = sum_c u[c,w]^2 (rounded u)
    __shared__ __align__(16) float s_o[K * SO_STRIDE];  // 20.8 KB output transpose

    const int tid  = threadIdx.x;
    const int wave = tid >> 6, lane = tid & 63;
    const int quad = lane >> 4, l16 = lane & 15;
    const int bh   = blockIdx.x;
    const int b    = bh >> 7, h = bh & 127;
    const int m0   = wave * 16;

    // ---- Phase P: prototype norms + ppsum (R7-verbatim) ----
    #pragma unroll
    for (int rd = 0; rd < 2; ++rd) {
        const int k = rd * 16 + wave;
        if (k < K) {
            const float* p = protos + k * C;
            const float a = p[lane], b2 = p[lane + 64];
            float ss = fmaf(a, a, b2 * b2);
            #pragma unroll
            for (int off = 32; off > 0; off >>= 1) ss += __shfl_xor(ss, off, 64);
            const float rp = 1.0f / fmaxf(sqrtf(ss), 1e-12f);
            const float q0 = bf_to_f(f2bf_bits(a * rp));
            const float q1 = bf_to_f(f2bf_bits(b2 * rp));
            float s2 = fmaf(q0, q0, q1 * q1);
            #pragma unroll
            for (int off = 32; off > 0; off >>= 1) s2 += __shfl_xor(s2, off, 64);
            if (lane == 0) { s_rp[k] = rp; s_pp[k] = s2; }
        }
    }

    f32x4 acc0 = {0.f, 0.f, 0.f, 0.f}, acc1 = {0.f, 0.f, 0.f, 0.f};
    float Sp = 0.f;
    bf16x8 bfrag[4][2];

    #pragma unroll
    for (int pass = 0; pass < 2; ++pass) {
        // ---- Stage: wave loads rows cc=wave*4+r (full W), computes rn in-wave,
        //      writes bf16(f*rn) to tile. No barrier between norm and staging. ----
        #pragma unroll
        for (int r = 0; r < 4; ++r) {
            const int cc = wave * 4 + r;           // tile row 0..63
            const int c  = pass * 64 + cc;
            const float* row = feats + ((size_t)((b * C + c) * H + h)) * W;
            const float4 f4 = ((const float4*)row)[lane];   // 1 KB/wave, coalesced
            float ss = fmaf(f4.x, f4.x, fmaf(f4.y, f4.y, fmaf(f4.z, f4.z, f4.w * f4.w)));
            #pragma unroll
            for (int off = 32; off > 0; off >>= 1) ss += __shfl_xor(ss, off, 64);
            const float rn = 1.0f / fmaxf(sqrtf(ss), 1e-12f);   // dim=1 (W-axis) norm
            const unsigned lo = f2bf_bits(f4.x * rn) | (f2bf_bits(f4.y * rn) << 16);
            const unsigned hi = f2bf_bits(f4.z * rn) | (f2bf_bits(f4.w * rn) << 16);
            // element idx = (lane*4)^swz, swz=((cc>>3)&3)<<4 -> word = (lane*2)^(swz>>1)
            const int word = cc * 128 + ((lane * 2) ^ (((cc >> 3) & 3) << 3));
            uint2 pk; pk.x = lo; pk.y = hi;
            *(uint2*)&s_u32[word] = pk;            // ds_write_b64, even-word aligned
        }
        __syncthreads();   // tile ready (pass 0: also s_rp/s_pp ready)

        if (pass == 0) {
            // ---- B-fragments from L2-hot protos (R7-verbatim) ----
            #pragma unroll
            for (int t = 0; t < 2; ++t) {
                const int k = t * 16 + l16;
                const float rp = (k < K) ? s_rp[k] : 0.0f;
                #pragma unroll
                for (int ch = 0; ch < 4; ++ch) {
                    bf16x8 f = {0, 0, 0, 0, 0, 0, 0, 0};
                    if (k < K) {
                        const float* pr = protos + k * C + ch * 32 + quad * 8;
                        const float4 pa = *(const float4*)(pr);
                        const float4 pb = *(const float4*)(pr + 4);
                        f[0] = (short)f2bf_bits(pa.x * rp);
                        f[1] = (short)f2bf_bits(pa.y * rp);
                        f[2] = (short)f2bf_bits(pa.z * rp);
                        f[3] = (short)f2bf_bits(pa.w * rp);
                        f[4] = (short)f2bf_bits(pb.x * rp);
                        f[5] = (short)f2bf_bits(pb.y * rp);
                        f[6] = (short)f2bf_bits(pb.z * rp);
                        f[7] = (short)f2bf_bits(pb.w * rp);
                    }
                    bfrag[ch][t] = f;
                }
            }
        }

        // ---- MFMA: A-frag af[j] = u[row = ch2*32+quad*8+j][w = m0+l16] ----
        // word = row*128 + ((m0+l16)>>1 ^ quad*8): quads hit disjoint bank octets,
        // even/odd l16 share a word (broadcast) -> conflict-free.
        const int wadrw = ((m0 + l16) >> 1) ^ (quad << 3);
        const unsigned sel = (unsigned)(l16 & 1);
        #pragma unroll
        for (int ch2 = 0; ch2 < 2; ++ch2) {
            bf16x8 af;
            #pragma unroll
            for (int j = 0; j < 8; ++j) {
                const int rowi = ch2 * 32 + quad * 8 + j;
                const unsigned v = s_u32[rowi * 128 + wadrw];
                af[j] = (short)(sel ? (v >> 16) : v);
                const float ur = __uint_as_float(sel ? (v & 0xffff0000u) : (v << 16));
                Sp = fmaf(ur, ur, Sp);
            }
            const int ch = pass * 2 + ch2;
            acc0 = __builtin_amdgcn_mfma_f32_16x16x32_bf16(af, bfrag[ch][0], acc0, 0, 0, 0);
            acc1 = __builtin_amdgcn_mfma_f32_16x16x32_bf16(af, bfrag[ch][1], acc1, 0, 0, 0);
        }
        __syncthreads();   // done reading tile; next pass may overwrite
    }

    // ---- S[w]: sum quad-partials (R7-verbatim) ----
    Sp += __shfl_xor(Sp, 16, 64);
    Sp += __shfl_xor(Sp, 32, 64);
    if (lane < 16) s_S[m0 + lane] = Sp;
    __syncthreads();

    // ---- Epilogue into padded LDS transpose (R7-verbatim) ----
    const float scale = fabsf(dscale[0]);
    const float pcol0 = s_pp[l16];
    const float pcol1 = (l16 < 4) ? s_pp[16 + l16] : 0.0f;
    #pragma unroll
    for (int r = 0; r < 4; ++r) {
        const int wl = m0 + quad * 4 + r;       // D row m = quad*4+r -> w
        const float Sm = s_S[wl];
        const float d20 = fmaxf(Sm + pcol0 - 2.0f * acc0[r], 0.f);
        s_o[l16 * SO_STRIDE + wl] = -scale * sqrtf(d20);
        if (l16 < 4) {
            const float d21 = fmaxf(Sm + pcol1 - 2.0f * acc1[r], 0.f);
            s_o[(16 + l16) * SO_STRIDE + wl] = -scale * sqrtf(d21);
        }
    }
    __syncthreads();

    // ---- Coalesced store: 20 k-rows x 256 w (R7-verbatim) ----
    for (int i = tid; i < K * (W / 4); i += 1024) {
        const int k = i >> 6, g = i & 63;
        const float4 v = *(const float4*)&s_o[k * SO_STRIDE + g * 4];
        *(float4*)(out + ((size_t)(b * K + k)) * HW + h * W + g * 4) = v;
    }
}

extern "C" void kernel_launch(void* const* d_in, const int* in_sizes, int n_in,
                              void* d_out, int out_size, void* d_ws, size_t ws_size,
                              hipStream_t stream) {
    const float* feats  = (const float*)d_in[0];
    const float* protos = (const float*)d_in[1];
    const float* dscale = (const float*)d_in[2];
    float* out = (float*)d_out;

    isomax_fused<<<B * H, 1024, 0, stream>>>(feats, protos, dscale, out);
}

// Round 9
// 86.627 us; speedup vs baseline: 1.0030x; 1.0030x over previous
//
#include <hip/hip_runtime.h>
#include <math.h>

// Problem dims (fixed by reference setup_inputs)
#define B 2
#define C 128
#define H 128
#define W 256
#define K 20
#define HW (H * W)
#define SO_STRIDE 260   // s_o row stride in floats (float4-aligned, bank-skewed)

typedef float f32x4 __attribute__((ext_vector_type(4)));
typedef short bf16x8 __attribute__((ext_vector_type(8)));

// round-to-nearest-even fp32 -> bf16 bits (finite inputs)
__device__ __forceinline__ unsigned f2bf_bits(float x) {
    unsigned u = __float_as_uint(x);
    return (u + 0x7FFFu + ((u >> 16) & 1u)) >> 16;
}
__device__ __forceinline__ float bf_to_f(unsigned bits) {
    return __uint_as_float(bits << 16);
}

// One block per (b,h): 1024 threads = 16 waves; wave = 16-w m-tile (m0 = wave*16).
// R8 skeleton (verified) restructured for ILP: loads batched ahead of use, the
// 6-step shuffle-reduce chains of 4 rows interleaved (ds_swizzle ~120cyc latency
// was serialized per-row in R7/R8 -> dominant cost). Single 64KB tile, one pass.
__global__ __launch_bounds__(1024) void isomax_fused(
    const float* __restrict__ feats, const float* __restrict__ protos,
    const float* __restrict__ dscale, float* __restrict__ out)
{
    __shared__ __align__(16) unsigned s_u32[C * 128];   // 64 KB bf16 tile [c][(w^swz)/2]
    __shared__ float s_rp[32];              // proto inv-norms
    __shared__ float s_pp[32];              // sum_c bf(pn[k,c])^2
    __shared__ float s_S[W];                // S[w]
    __shared__ __align__(16) float s_o[K * SO_STRIDE];  // 20.8 KB output transpose

    const int tid  = threadIdx.x;
    const int wave = tid >> 6, lane = tid & 63;
    const int quad = lane >> 4, l16 = lane & 15;
    const int bh   = blockIdx.x;
    const int b    = bh >> 7, h = bh & 127;
    const int m0   = wave * 16;

    const float* fb = feats + (size_t)b * C * HW + h * W;   // row c at fb + c*HW

    // ---- Issue group-A feature loads (4 rows) + proto loads, all independent ----
    const int cA = wave * 8;
    float4 fA[4];
    #pragma unroll
    for (int r = 0; r < 4; ++r)
        fA[r] = ((const float4*)(fb + (size_t)(cA + r) * HW))[lane];

    const int k0 = wave;                 // < 16 < K, always valid
    const int k1 = 16 + (wave & 3);      // uniform; only waves 0..3 write results
    const float pa0 = protos[k0 * C + lane], pb0 = protos[k0 * C + lane + 64];
    const float pa1 = protos[k1 * C + lane], pb1 = protos[k1 * C + lane + 64];

    // ---- Issue group-B feature loads before any reduction work ----
    const int cB = cA + 4;
    float4 fB[4];
    #pragma unroll
    for (int r = 0; r < 4; ++r)
        fB[r] = ((const float4*)(fb + (size_t)(cB + r) * HW))[lane];

    // ---- Phase P: two interleaved proto-norm chains ----
    {
        float ss0 = fmaf(pa0, pa0, pb0 * pb0);
        float ss1 = fmaf(pa1, pa1, pb1 * pb1);
        #pragma unroll
        for (int off = 32; off > 0; off >>= 1) {
            ss0 += __shfl_xor(ss0, off, 64);
            ss1 += __shfl_xor(ss1, off, 64);
        }
        const float rp0 = 1.0f / fmaxf(sqrtf(ss0), 1e-12f);
        const float rp1 = 1.0f / fmaxf(sqrtf(ss1), 1e-12f);
        const float q00 = bf_to_f(f2bf_bits(pa0 * rp0));
        const float q01 = bf_to_f(f2bf_bits(pb0 * rp0));
        const float q10 = bf_to_f(f2bf_bits(pa1 * rp1));
        const float q11 = bf_to_f(f2bf_bits(pb1 * rp1));
        float s20 = fmaf(q00, q00, q01 * q01);
        float s21 = fmaf(q10, q10, q11 * q11);
        #pragma unroll
        for (int off = 32; off > 0; off >>= 1) {
            s20 += __shfl_xor(s20, off, 64);
            s21 += __shfl_xor(s21, off, 64);
        }
        if (lane == 0) {
            s_rp[k0] = rp0; s_pp[k0] = s20;
            if (wave < 4) { s_rp[k1] = rp1; s_pp[k1] = s21; }
        }
    }

    // ---- Process a 4-row group: interleaved shuffle chains, then stage ----
    #define PROC_GROUP(fR, c0)                                                     \
    {                                                                              \
        float ss[4];                                                               \
        _Pragma("unroll")                                                          \
        for (int r = 0; r < 4; ++r) {                                              \
            const float4 v = fR[r];                                                \
            ss[r] = fmaf(v.x, v.x, fmaf(v.y, v.y, fmaf(v.z, v.z, v.w * v.w)));     \
        }                                                                          \
        _Pragma("unroll")                                                          \
        for (int off = 32; off > 0; off >>= 1) {                                   \
            _Pragma("unroll")                                                      \
            for (int r = 0; r < 4; ++r) ss[r] += __shfl_xor(ss[r], off, 64);       \
        }                                                                          \
        _Pragma("unroll")                                                          \
        for (int r = 0; r < 4; ++r) {                                              \
            const float rn = 1.0f / fmaxf(sqrtf(ss[r]), 1e-12f);                   \
            const float4 v = fR[r];                                                \
            const unsigned lo = f2bf_bits(v.x * rn) | (f2bf_bits(v.y * rn) << 16); \
            const unsigned hi = f2bf_bits(v.z * rn) | (f2bf_bits(v.w * rn) << 16); \
            const int c = (c0) + r;                                                \
            const int word = c * 128 + ((lane * 2) ^ (((c >> 3) & 3) << 3));       \
            uint2 pk; pk.x = lo; pk.y = hi;                                        \
            *(uint2*)&s_u32[word] = pk;                                            \
        }                                                                          \
    }

    PROC_GROUP(fA, cA)
    PROC_GROUP(fB, cB)
    __syncthreads();   // tile + s_rp/s_pp ready

    // ---- B-fragments from L2-hot protos (R7/R8-verbatim mapping) ----
    bf16x8 bfrag[4][2];
    #pragma unroll
    for (int t = 0; t < 2; ++t) {
        const int k = t * 16 + l16;
        const float rp = (k < K) ? s_rp[k] : 0.0f;
        #pragma unroll
        for (int ch = 0; ch < 4; ++ch) {
            bf16x8 f = {0, 0, 0, 0, 0, 0, 0, 0};
            if (k < K) {
                const float* pr = protos + k * C + ch * 32 + quad * 8;
                const float4 pa = *(const float4*)(pr);
                const float4 pb = *(const float4*)(pr + 4);
                f[0] = (short)f2bf_bits(pa.x * rp);
                f[1] = (short)f2bf_bits(pa.y * rp);
                f[2] = (short)f2bf_bits(pa.z * rp);
                f[3] = (short)f2bf_bits(pa.w * rp);
                f[4] = (short)f2bf_bits(pb.x * rp);
                f[5] = (short)f2bf_bits(pb.y * rp);
                f[6] = (short)f2bf_bits(pb.z * rp);
                f[7] = (short)f2bf_bits(pb.w * rp);
            }
            bfrag[ch][t] = f;
        }
    }

    // ---- MFMA: A-frags from tile (R8-verified addressing), 8 MFMAs ----
    f32x4 acc0 = {0.f, 0.f, 0.f, 0.f}, acc1 = {0.f, 0.f, 0.f, 0.f};
    float Sp = 0.f;
    const int wadrw = ((m0 + l16) >> 1) ^ (quad << 3);
    const unsigned sel = (unsigned)(l16 & 1);
    #pragma unroll
    for (int ch = 0; ch < 4; ++ch) {
        bf16x8 af;
        #pragma unroll
        for (int j = 0; j < 8; ++j) {
            const int rowi = ch * 32 + quad * 8 + j;
            const unsigned v = s_u32[rowi * 128 + wadrw];
            af[j] = (short)(sel ? (v >> 16) : v);
            const float ur = __uint_as_float(sel ? (v & 0xffff0000u) : (v << 16));
            Sp = fmaf(ur, ur, Sp);
        }
        acc0 = __builtin_amdgcn_mfma_f32_16x16x32_bf16(af, bfrag[ch][0], acc0, 0, 0, 0);
        acc1 = __builtin_amdgcn_mfma_f32_16x16x32_bf16(af, bfrag[ch][1], acc1, 0, 0, 0);
    }

    // ---- S[w]: sum quad-partials (R7-verbatim) ----
    Sp += __shfl_xor(Sp, 16, 64);
    Sp += __shfl_xor(Sp, 32, 64);
    if (lane < 16) s_S[m0 + lane] = Sp;
    __syncthreads();

    // ---- Epilogue into padded LDS transpose (R7-verbatim) ----
    const float scale = fabsf(dscale[0]);
    const float pcol0 = s_pp[l16];
    const float pcol1 = (l16 < 4) ? s_pp[16 + l16] : 0.0f;
    #pragma unroll
    for (int r = 0; r < 4; ++r) {
        const int wl = m0 + quad * 4 + r;
        const float Sm = s_S[wl];
        const float d20 = fmaxf(Sm + pcol0 - 2.0f * acc0[r], 0.f);
        s_o[l16 * SO_STRIDE + wl] = -scale * sqrtf(d20);
        if (l16 < 4) {
            const float d21 = fmaxf(Sm + pcol1 - 2.0f * acc1[r], 0.f);
            s_o[(16 + l16) * SO_STRIDE + wl] = -scale * sqrtf(d21);
        }
    }
    __syncthreads();

    // ---- Coalesced store: 20 k-rows x 256 w (R7-verbatim) ----
    for (int i = tid; i < K * (W / 4); i += 1024) {
        const int k = i >> 6, g = i & 63;
        const float4 v = *(const float4*)&s_o[k * SO_STRIDE + g * 4];
        *(float4*)(out + ((size_t)(b * K + k)) * HW + h * W + g * 4) = v;
    }
}

extern "C" void kernel_launch(void* const* d_in, const int* in_sizes, int n_in,
                              void* d_out, int out_size, void* d_ws, size_t ws_size,
                              hipStream_t stream) {
    const float* feats  = (const float*)d_in[0];
    const float* protos = (const float*)d_in[1];
    const float* dscale = (const float*)d_in[2];
    float* out = (float*)d_out;

    isomax_fused<<<B * H, 1024, 0, stream>>>(feats, protos, dscale, out);
}